// Round 6
// baseline (7554.962 us; speedup 1.0000x reference)
//
#include <hip/hip_runtime.h>
#include <hip/hip_bf16.h>
#include <stdint.h>

// ---------------------------------------------------------------------------
// Peephole LSTM, SEQ=512, B=64, I=H=1024.  Persistent-kernel, 256 blocks.
// Round-15: R14 base (7.42ms) + SLICE-GROUPED exchange + per-producer h-flags
//           with PIPELINED slice pulls.
//  * Exchange buffers reorganized [grp][cg][row16][col16] (512B/producer
//    tile, contiguous): producer stores = 512B contiguous (4 lines, faster
//    drain vs 16 scattered); consumer pulls = 128B/thread contiguous.
//  * h-exchange: per-producer flag (epoch=t+1, monotone).  Consumer thread
//    tid pulls slice tid>>2 as soon as THAT producer's flag lands ->
//    pull overlaps detection of stragglers (removes the serialized
//    detect->bulk-pull RT).  Flags polled, payload read once (R10/R13
//    lesson); per-slice visibility: flag stored after producer vmcnt(0)
//    drain (R12-verified discipline).
//  * c-exchange: counter barrier kept (phase B needs all 64 slices at
//    once); pulls retargeted to slice layout (frag (wv,kg,kcc) -> slice
//    wv*16+kcc*2+(kg>>1), 16B chunk (kg&1)); sc_ carry units UNCHANGED
//    (unit = wv*32+kcc*4+kg, verified bijection).
//  * WAR safety: double-buffered slots + per-step c-counter barrier keep
//    any producer <=1 step ahead of any consumer slot-wise (see comments).
//  * Everything else byte-identical to R14 (verified).
// ---------------------------------------------------------------------------

typedef __attribute__((ext_vector_type(8))) short short8;
typedef __attribute__((ext_vector_type(4))) float f32x4;
typedef __attribute__((ext_vector_type(4))) unsigned int uint4v;

#define OFF_WB   25165824u   // WA: 64cg*4g*96kc*64l*8e bf16
#define OFF_HBF  27262976u   // WB: 2097152
#define OFF_CBF  27525120u   // hbf: 2 slots * 131072 B (slice-grouped)
#define OFF_BAR  27787264u   // cbf: 2 slots * 131072 B
#define WS_NEED  27918336u   // bar: c counters @256B; h flags @ +16KB

__device__ __forceinline__ short bfc(float f) {
  __hip_bfloat16 h = __float2bfloat16(f);
  return *reinterpret_cast<short*>(&h);
}
__device__ __forceinline__ unsigned pk2(float a, float b) {
  __hip_bfloat16 ha = __float2bfloat16(a), hb = __float2bfloat16(b);
  unsigned short ua = *reinterpret_cast<unsigned short*>(&ha);
  unsigned short ub = *reinterpret_cast<unsigned short*>(&hb);
  return (unsigned)ua | ((unsigned)ub << 16);
}
__device__ __forceinline__ float sig_fast(float v) {
  return __fdividef(1.f, 1.f + __expf(-v));
}
__device__ __forceinline__ float tanh_fast(float v) {
  float a = fabsf(v);
  float e = __expf(-2.f * a);
  float t = (1.f - e) * __fdividef(1.f, 1.f + e);
  return copysignf(t, v);
}

// ---- L1+L2-bypassing accesses (coherent at L3 across XCDs) ----
__device__ __forceinline__ uint4v ldg_sc(const void* p) {
  uint4v r;
  asm volatile("global_load_dwordx4 %0, %1, off sc0 sc1" : "=v"(r) : "v"(p));
  return r;
}
__device__ __forceinline__ unsigned poll_sc(const unsigned* p) {
  unsigned r;
  asm volatile("global_load_dword %0, %1, off sc0 sc1\n\ts_waitcnt vmcnt(0)"
               : "=v"(r) : "v"(p) : "memory");
  return r;
}
__device__ __forceinline__ void stg_u32_sc(unsigned* p, unsigned v) {
  asm volatile("global_store_dword %0, %1, off sc0 sc1" :: "v"(p), "v"(v) : "memory");
}

// ---------------------------------------------------------------------------
// prep: pack weights + init slice-grouped h0/c0 (slot 0) + zero bar region.
// WA slot ((cg*4+g)*96+kc)*64+l holds W_g[j=cg*16+(l&15)][kc*32+8*(l>>4)+e]
// WB slot ((cg*4+v)*8+kc)*64+l holds Wo[j][2048 + v*256+kc*32+8*(l>>4)+e].
// h/c slot layout: u32 idx ((grp*64+cg)*128 + r16*8 + cpr) = pair (2 bf16).
// ---------------------------------------------------------------------------
#define Z0 1310720LL
#define Z1 131072LL
#define Z2 32768LL
#define Z3 32768LL

__global__ __launch_bounds__(256)
void prep_kernel(const float* __restrict__ h0, const float* __restrict__ c0,
                 const float* __restrict__ Ww, const float* __restrict__ Wf,
                 const float* __restrict__ Wc, const float* __restrict__ Wo,
                 char* __restrict__ ws) {
  __hip_bfloat16* WA  = (__hip_bfloat16*)ws;
  __hip_bfloat16* WB  = (__hip_bfloat16*)(ws + OFF_WB);
  unsigned* hbf32 = (unsigned*)(ws + OFF_HBF);   // slot 0 = first 32768 u32
  unsigned* cbf32 = (unsigned*)(ws + OFF_CBF);
  unsigned* bar   = (unsigned*)(ws + OFF_BAR);

  const long long total = Z0 + Z1 + Z2 + Z3;
  for (long long idx = (long long)blockIdx.x * 256 + threadIdx.x; idx < total;
       idx += (long long)gridDim.x * 256) {
    if (idx < Z0) {
      int l  = (int)(idx & 63);
      int s  = (int)((idx >> 6) % 320);
      int cg = (int)(idx / (320 * 64));
      int g, kc;
      if (s < 96)       { g = 0; kc = s; }
      else if (s < 192) { g = 1; kc = s - 96; }
      else if (s < 256) { g = 2; kc = s - 192; }
      else              { g = 3; kc = s - 256; }
      int j  = cg * 16 + (l & 15);
      int kb = kc * 32 + ((l >> 4) << 3);
      const float* W; int rl;
      if (g == 0)      { W = Ww; rl = 3072; }
      else if (g == 1) { W = Wf; rl = 3072; }
      else if (g == 2) { W = Wc; rl = 2048; }
      else             { W = Wo; rl = 3072; }
      const float* src = W + (size_t)j * rl + kb;
      __hip_bfloat16* dst = WA + ((((size_t)cg * 4 + g) * 96 + kc) * 64 + l) * 8;
#pragma unroll
      for (int e = 0; e < 8; ++e) dst[e] = __float2bfloat16(src[e]);
    } else if (idx < Z0 + Z1) {
      long long q = idx - Z0;
      int l  = (int)(q & 63);
      int kc = (int)((q >> 6) & 7);
      int v  = (int)((q >> 9) & 3);
      int cg = (int)(q >> 11);
      int j  = cg * 16 + (l & 15);
      int k  = 2048 + v * 256 + kc * 32 + ((l >> 4) << 3);
      const float* src = Wo + (size_t)j * 3072 + k;
      __hip_bfloat16* dst = WB + ((((size_t)cg * 4 + v) * 8 + kc) * 64 + l) * 8;
#pragma unroll
      for (int e = 0; e < 8; ++e) dst[e] = __float2bfloat16(src[e]);
    } else if (idx < Z0 + Z1 + Z2) {
      int u  = (int)(idx - (Z0 + Z1));        // pair index: R=u>>9, pp=u&511
      int R  = u >> 9, pp = u & 511;
      int cg = pp >> 3, cpr = pp & 7;
      int dst = ((R >> 4) * 64 + cg) * 128 + (R & 15) * 8 + cpr;
      const float* hs = h0 + (size_t)R * 1024 + 2 * pp;
      const float* cs = c0 + (size_t)R * 1024 + 2 * pp;
      hbf32[dst] = pk2(hs[0], hs[1]);
      cbf32[dst] = pk2(cs[0], cs[1]);
    } else {
      int i = (int)(idx - (Z0 + Z1 + Z2));
      bar[i] = 0u;
    }
  }
}

// ---------------------------------------------------------------------------
// main persistent kernel
// ---------------------------------------------------------------------------
__global__ __launch_bounds__(256, 1)
void lstm_kernel(const float* __restrict__ x,  const float* __restrict__ c0,
                 const float* __restrict__ bw, const float* __restrict__ bfg,
                 const float* __restrict__ bc, const float* __restrict__ bo,
                 float* __restrict__ out, char* __restrict__ ws) {
  char*     hbf   = ws + OFF_HBF;
  char*     cbf   = ws + OFF_CBF;
  unsigned* cctr  = (unsigned*)(ws + OFF_BAR);          // + grp*64
  unsigned* hflag = (unsigned*)(ws + OFF_BAR) + 4096;   // + (grp*64+cg)*16

  const int tid  = threadIdx.x;
  const int l    = tid & 63;
  const int wv   = tid >> 6;                         // wave = gate (A) / K-split (B)
  const int b    = blockIdx.x;
  const int cg   = ((b & 7) << 3) | ((b >> 3) & 7);  // XCD-partitioned col-group
  const int grp  = b >> 6;                           // batch row-group (0..3)
  const int col  = l & 15;
  const int kg   = l >> 4;
  const int row16 = col;                             // A-frag row within tile
  const int srow  = row16 & 7;                       // LDS swizzle key
  const int j    = (cg << 4) + col;
  const int pslice = tid >> 2;                       // slice pulled by this thread
  const int pq     = tid & 3;                        // its row quarter

  const float* bptr = (wv == 0) ? bw : (wv == 1) ? bfg : (wv == 2) ? bc : bo;
  const float bias = bptr[j];

  const short8* BW = (const short8*)ws + ((size_t)(cg * 4 + wv)) * 96 * 64 + l;
  const short8* BO = (const short8*)(ws + OFF_WB) + ((size_t)(cg * 4 + wv)) * 8 * 64 + l;

  __shared__ __align__(16) char sx[32768];   // x tile  [16][1024] bf16, swizzled
  __shared__ __align__(16) char sh[32768];   // h tile
  __shared__ __align__(16) char sc_[32768];  // c tile (carried across steps)
  __shared__ float lds[5][16][17];

  // combine mapping: tid<128 owns (crow, 2 cols)
  const int crow = tid >> 3;
  const int cpr  = tid & 7;
  const int coff = ((grp * 16 + crow) << 10) + (cg << 4) + 2 * cpr;
  float c_reg0 = 0.f, c_reg1 = 0.f;
  if (tid < 128) { c_reg0 = c0[coff]; c_reg1 = c0[coff + 1]; }
  // this block's producer targets (slice-grouped, 512B tile)
  char* hDst = hbf /*+slot*/ + ((size_t)(grp * 64 + cg)) * 512 + crow * 32 + cpr * 4;
  char* cDst = cbf /*+slot*/ + ((size_t)(grp * 64 + cg)) * 512 + crow * 32 + cpr * 4;
  unsigned* myflag = hflag + (grp * 64 + cg) * 16;

  // ---- startup: stage c0 tile (slice-grouped slot 0) -> swizzled sc_ ----
  {
    const char* csl = cbf + ((size_t)(grp * 64 + pslice)) * 512 + pq * 128;
    uint4v cv[8];
#pragma unroll
    for (int jj = 0; jj < 8; ++jj) cv[jj] = ldg_sc(csl + jj * 16);
    asm volatile("s_waitcnt vmcnt(0)" ::: "memory");
    __builtin_amdgcn_sched_barrier(0);
#pragma unroll
    for (int jj = 0; jj < 8; ++jj) {
      int r = pq * 4 + (jj >> 1);
      int u = pslice * 2 + (jj & 1);
      *(uint4v*)(sc_ + r * 2048 + ((u ^ (r & 7)) << 4)) = cv[jj];
    }
  }
  // ---- startup: stage x(0) tile ----
  {
    const float* xs = x + (size_t)grp * 16384;
#pragma unroll
    for (int i = 0; i < 8; ++i) {
      int q = i * 256 + tid;
      const float* s = xs + q * 8;
      float4 f0 = *(const float4*)s;
      float4 f1 = *(const float4*)(s + 4);
      short8 v;
      v[0] = bfc(f0.x); v[1] = bfc(f0.y); v[2] = bfc(f0.z); v[3] = bfc(f0.w);
      v[4] = bfc(f1.x); v[5] = bfc(f1.y); v[6] = bfc(f1.z); v[7] = bfc(f1.w);
      int rw = q >> 7, kb = (q & 127) ^ (rw & 7);
      *(short8*)(sx + rw * 2048 + (kb << 4)) = v;
    }
  }

  // ---- pin recurrent-path weight fragments in registers (loop-invariant) ----
  short8 WH[32];
#pragma unroll
  for (int f = 0; f < 32; ++f) WH[f] = BW[(size_t)(32 + f) * 64];
  short8 WBo[8];
#pragma unroll
  for (int k = 0; k < 8; ++k) WBo[k] = BO[(size_t)k * 64];

  __syncthreads();                     // startup sx/sc_ visible block-wide

  for (int t = 0; t < 512; ++t) {
    f32x4 acc[4];
#pragma unroll
    for (int u = 0; u < 4; ++u) acc[u] = (f32x4){0.f, 0.f, 0.f, 0.f};

    // ---- phase A, x part (sx staged in prev iter's c-gap / startup) ----
#pragma unroll
    for (int kc = 0; kc < 8; ++kc)
#pragma unroll
      for (int u = 0; u < 4; ++u) {
        int f = kc * 4 + u;
        short8 a = *(const short8*)(sx + row16 * 2048 + ((((f << 2) + kg) ^ srow) << 4));
        acc[u] = __builtin_amdgcn_mfma_f32_16x16x32_bf16(a, BW[(size_t)f * 64], acc[u], 0, 0, 0);
      }
    // ---- phase A, c part (write & forget gates) — pre-wait (R14) ----
    if (wv < 2) {
#pragma unroll
      for (int kc = 0; kc < 8; ++kc)
#pragma unroll
        for (int u = 0; u < 4; ++u) {
          int f = kc * 4 + u;
          short8 a = *(const short8*)(sc_ + row16 * 2048 + ((((f << 2) + kg) ^ srow) << 4));
          acc[u] = __builtin_amdgcn_mfma_f32_16x16x32_bf16(a, BW[(size_t)(64 + f) * 64], acc[u], 0, 0, 0);
        }
    }

    // ---- h pull: per-slice flag poll + pipelined pull -> swizzled sh ----
    // h(t-1) lives in slot t&1 with flag value t (posted post-drain).
    {
      const char* hsl = hbf + (size_t)(t & 1) * 131072 +
                        ((size_t)(grp * 64 + pslice)) * 512 + pq * 128;
      const unsigned* pf = hflag + (grp * 64 + pslice) * 16;
      unsigned spins = 0;
      for (;;) {
        unsigned v = poll_sc(pf);
        if ((int)v >= t) break;
        __builtin_amdgcn_s_sleep(1);
        if (++spins > (1u << 18)) break;             // failsafe: fail loud
      }
      uint4v hv[8];
#pragma unroll
      for (int jj = 0; jj < 8; ++jj) hv[jj] = ldg_sc(hsl + jj * 16);
      asm volatile("s_waitcnt vmcnt(0)" ::: "memory");
      __builtin_amdgcn_sched_barrier(0);
#pragma unroll
      for (int jj = 0; jj < 8; ++jj) {
        int r = pq * 4 + (jj >> 1);
        int u = pslice * 2 + (jj & 1);
        *(uint4v*)(sh + r * 2048 + ((u ^ (r & 7)) << 4)) = hv[jj];
      }
    }
    __syncthreads();

    // ---- phase A, h part (all gates) — register-pinned fragments ----
#pragma unroll
    for (int kc = 0; kc < 8; ++kc)
#pragma unroll
      for (int u = 0; u < 4; ++u) {
        int f = kc * 4 + u;
        short8 a = *(const short8*)(sh + row16 * 2048 + ((((f << 2) + kg) ^ srow) << 4));
        acc[u] = __builtin_amdgcn_mfma_f32_16x16x32_bf16(a, WH[f], acc[u], 0, 0, 0);
      }
    {
      const int dbuf = (wv == 3) ? 4 : wv;
#pragma unroll
      for (int i = 0; i < 4; ++i)
        lds[dbuf][kg * 4 + i][col] = acc[0][i] + acc[1][i] + acc[2][i] + acc[3][i] + bias;
    }
    __syncthreads();

    // ---- c_new combine; slice-grouped store (512B contiguous/block) ----
    if (tid < 128) {
      float aw0 = lds[0][crow][2 * cpr], aw1 = lds[0][crow][2 * cpr + 1];
      float af0 = lds[1][crow][2 * cpr], af1 = lds[1][crow][2 * cpr + 1];
      float ag0 = lds[2][crow][2 * cpr], ag1 = lds[2][crow][2 * cpr + 1];
      float cn0 = sig_fast(af0) * c_reg0 + sig_fast(aw0) * tanh_fast(ag0);
      float cn1 = sig_fast(af1) * c_reg1 + sig_fast(aw1) * tanh_fast(ag1);
      c_reg0 = cn0; c_reg1 = cn1;
      stg_u32_sc((unsigned*)(cDst + (size_t)((t & 1) ^ 1) * 131072), pk2(cn0, cn1));
    }
    // arrive(c): drain + block-sync + one atomicAdd (R14-verified ordering)
    asm volatile("s_waitcnt vmcnt(0)" ::: "memory");
    __syncthreads();
    if (tid == 0)
      __hip_atomic_fetch_add(cctr + grp * 64, 1u,
                             __ATOMIC_RELAXED, __HIP_MEMORY_SCOPE_AGENT);

    // ---- fill the c-exchange gap: stage x(t+1) (sx dead here) ----
    if (t < 511) {
      const float* xs = x + (((size_t)t + 1) << 16) + (size_t)grp * 16384;
#pragma unroll
      for (int i = 0; i < 8; ++i) {
        int q = i * 256 + tid;
        const float* s = xs + q * 8;
        float4 f0 = *(const float4*)s;
        float4 f1 = *(const float4*)(s + 4);
        short8 v;
        v[0] = bfc(f0.x); v[1] = bfc(f0.y); v[2] = bfc(f0.z); v[3] = bfc(f0.w);
        v[4] = bfc(f1.x); v[5] = bfc(f1.y); v[6] = bfc(f1.z); v[7] = bfc(f1.w);
        int rw = q >> 7, kb = (q & 127) ^ (rw & 7);
        *(short8*)(sx + rw * 2048 + (kb << 4)) = v;
      }
    }

    // wait(c): counter reaches 64*(t+1)
    if (tid == 0) {
      const unsigned tgt = ((unsigned)t + 1u) * 64u;
      unsigned spins = 0;
      for (;;) {
        unsigned v = poll_sc(cctr + grp * 64);
        if (v >= tgt) break;
        __builtin_amdgcn_s_sleep(1);
        if (++spins > (1u << 18)) break;             // failsafe: fail loud
      }
    }
    __syncthreads();
    __builtin_amdgcn_sched_barrier(0);

    // ---- phase B: slice-layout c pull feeds MFMA directly; carry to sc_ ----
    {
      const char* cslot = cbf + (size_t)((t & 1) ^ 1) * 131072 +
                          (size_t)grp * 32768 + row16 * 32 + (kg & 1) * 16;
      uint4v ca[8];
#pragma unroll
      for (int kcc = 0; kcc < 8; ++kcc) {
        int s = wv * 16 + kcc * 2 + (kg >> 1);
        ca[kcc] = ldg_sc(cslot + (size_t)s * 512);
      }
      asm volatile("s_waitcnt vmcnt(0)" ::: "memory");
      __builtin_amdgcn_sched_barrier(0);
      f32x4 a0 = {0.f, 0.f, 0.f, 0.f}, a1 = {0.f, 0.f, 0.f, 0.f};
#pragma unroll
      for (int kcc = 0; kcc < 8; ++kcc) {
        short8 a = __builtin_bit_cast(short8, ca[kcc]);
        if (kcc & 1) a1 = __builtin_amdgcn_mfma_f32_16x16x32_bf16(a, WBo[kcc], a1, 0, 0, 0);
        else         a0 = __builtin_amdgcn_mfma_f32_16x16x32_bf16(a, WBo[kcc], a0, 0, 0, 0);
      }
      // carry write: unit = wv*32 + kcc*4 + kg (verified bijection over tid)
      const int ub = wv * 32 + kg;
#pragma unroll
      for (int kcc = 0; kcc < 8; ++kcc)
        *(uint4v*)(sc_ + row16 * 2048 + (((ub + kcc * 4) ^ srow) << 4)) = ca[kcc];
#pragma unroll
      for (int i = 0; i < 4; ++i)
        lds[wv][kg * 4 + i][col] = a0[i] + a1[i];
    }
    __syncthreads();

    // ---- o combine, h_new; slice store; drain; post own h flag ----
    float h0v = 0.f, h1v = 0.f;
    if (tid < 128) {
      int c0i = 2 * cpr, c1i = 2 * cpr + 1;
      float s0 = lds[0][crow][c0i] + lds[1][crow][c0i] + lds[2][crow][c0i] +
                 lds[3][crow][c0i] + lds[4][crow][c0i];
      float s1 = lds[0][crow][c1i] + lds[1][crow][c1i] + lds[2][crow][c1i] +
                 lds[3][crow][c1i] + lds[4][crow][c1i];
      float o0 = sig_fast(s0), o1 = sig_fast(s1);
      h0v = o0 * tanh_fast(c_reg0);
      h1v = o1 * tanh_fast(c_reg1);
      stg_u32_sc((unsigned*)(hDst + (size_t)((t & 1) ^ 1) * 131072), pk2(h0v, h1v));
    }
    asm volatile("s_waitcnt vmcnt(0)" ::: "memory");   // own h tile at L3
    __syncthreads();
    if (tid == 0) stg_u32_sc(myflag, (unsigned)t + 1u);

    if (tid < 128) {
      float2 hv; hv.x = h0v; hv.y = h1v;
      *(float2*)(out + ((size_t)t << 16) + coff) = hv;
      if (t == 511) {                    // finals: owner writes directly
        *(float2*)(out + ((size_t)512 << 16) + coff) = hv;
        float2 cv; cv.x = c_reg0; cv.y = c_reg1;
        *(float2*)(out + ((size_t)512 << 16) + 65536 + coff) = cv;
      }
    }
  }
}

extern "C" void kernel_launch(void* const* d_in, const int* in_sizes, int n_in,
                              void* d_out, int out_size, void* d_ws, size_t ws_size,
                              hipStream_t stream) {
  (void)in_sizes; (void)n_in; (void)out_size;
  const float* x  = (const float*)d_in[0];
  const float* h0 = (const float*)d_in[1];
  const float* c0 = (const float*)d_in[2];
  const float* Ww = (const float*)d_in[3];
  const float* bw = (const float*)d_in[4];
  const float* Wf = (const float*)d_in[5];
  const float* bfg= (const float*)d_in[6];
  const float* Wc = (const float*)d_in[7];
  const float* bc = (const float*)d_in[8];
  const float* Wo = (const float*)d_in[9];
  const float* bo = (const float*)d_in[10];

  if (ws_size < (size_t)WS_NEED) return;  // leaves poison -> loud failure

  prep_kernel<<<dim3(2048), dim3(256), 0, stream>>>(h0, c0, Ww, Wf, Wc, Wo,
                                                    (char*)d_ws);
  lstm_kernel<<<dim3(256), dim3(256), 0, stream>>>(x, c0, bw, bfg, bc, bo,
                                                   (float*)d_out, (char*)d_ws);
}

// Round 7
// 6937.783 us; speedup vs baseline: 1.0890x; 1.0890x over previous
//
#include <hip/hip_runtime.h>
#include <hip/hip_bf16.h>
#include <stdint.h>

// ---------------------------------------------------------------------------
// Peephole LSTM, SEQ=512, B=64, I=H=1024.  Persistent-kernel, 256 blocks.
// Round-16: R14 base (verified 7.42ms) + WAVE-LOCAL c-exchange gating.
//  * R15 post-mortem: slice-pipelined h pulls neutral-negative; bank
//    conflicts +18% from new staging. R14 structure restored wholesale.
//  * Key observation: phase B's wave wv consumes ONLY c K-slice
//    [wv*256,(wv+1)*256) = 16 producer tiles.  R14 gated phase B on a
//    full-group counter (max over 64 producers + block barrier).  Now:
//    per-producer c-flags; each wave polls its OWN 16 producers
//    (lanes 0-15, one coalesced round) and starts MFMAs immediately.
//    max-of-16 < max-of-64 straggler tax; waves de-serialize.
//  * LDS hazard audit: lds[0..4] combine reads happen before arrive(c)'s
//    __syncthreads (protects phase-B lds[wv] overwrite); sc_ phase-B
//    writes vs next-step cA reads protected by post-B __syncthreads;
//    sx gap-staging vs xA reads protected by arrive(c) sync + next-step
//    post-h-stage sync.  c slot WAR: consumer's step-t read completes
//    before producer's t+2 write via the h(t+1) dependency chain.
//  * c payload: slice-grouped [grp][cg] 512B tiles (R15-verified math),
//    2 slots.  h exchange byte-identical to R14 (atomic counter, bulk
//    pull, original swizzles).  Startup sc_ from c0 in-kernel (R13 math).
// ---------------------------------------------------------------------------

typedef __attribute__((ext_vector_type(8))) short short8;
typedef __attribute__((ext_vector_type(4))) float f32x4;
typedef __attribute__((ext_vector_type(4))) unsigned int uint4v;

#define OFF_WB   25165824u   // WA: 64cg*4g*96kc*64l*8e bf16
#define OFF_HBF  27262976u   // WB: 2097152
#define OFF_CBF  27525120u   // hbf: 2 slots * 131072 (row-major, R14)
#define OFF_BAR  27787264u   // cbf: 2 slots * 131072 (slice-grouped)
#define WS_NEED  27918336u   // bar: hctr @ grp*64; cflag @ +4096 dwords

__device__ __forceinline__ short bfc(float f) {
  __hip_bfloat16 h = __float2bfloat16(f);
  return *reinterpret_cast<short*>(&h);
}
__device__ __forceinline__ unsigned pk2(float a, float b) {
  __hip_bfloat16 ha = __float2bfloat16(a), hb = __float2bfloat16(b);
  unsigned short ua = *reinterpret_cast<unsigned short*>(&ha);
  unsigned short ub = *reinterpret_cast<unsigned short*>(&hb);
  return (unsigned)ua | ((unsigned)ub << 16);
}
__device__ __forceinline__ float sig_fast(float v) {
  return __fdividef(1.f, 1.f + __expf(-v));
}
__device__ __forceinline__ float tanh_fast(float v) {
  float a = fabsf(v);
  float e = __expf(-2.f * a);
  float t = (1.f - e) * __fdividef(1.f, 1.f + e);
  return copysignf(t, v);
}

// ---- L1+L2-bypassing accesses (coherent at L3 across XCDs) ----
__device__ __forceinline__ uint4v ldg_sc(const void* p) {
  uint4v r;
  asm volatile("global_load_dwordx4 %0, %1, off sc0 sc1" : "=v"(r) : "v"(p));
  return r;
}
__device__ __forceinline__ unsigned poll_sc(const unsigned* p) {
  unsigned r;
  asm volatile("global_load_dword %0, %1, off sc0 sc1\n\ts_waitcnt vmcnt(0)"
               : "=v"(r) : "v"(p) : "memory");
  return r;
}
__device__ __forceinline__ void stg_u32_sc(unsigned* p, unsigned v) {
  asm volatile("global_store_dword %0, %1, off sc0 sc1" :: "v"(p), "v"(v) : "memory");
}

// ---------------------------------------------------------------------------
// prep: pack weights + row-major h0 slot0 + zero bar region.
// WA slot ((cg*4+g)*96+kc)*64+l holds W_g[j=cg*16+(l&15)][kc*32+8*(l>>4)+e]
// WB slot ((cg*4+v)*8+kc)*64+l holds Wo[j][2048 + v*256+kc*32+8*(l>>4)+e].
// ---------------------------------------------------------------------------
#define Z0 1310720LL
#define Z1 131072LL
#define Z2 65536LL
#define Z3 32768LL

__global__ __launch_bounds__(256)
void prep_kernel(const float* __restrict__ h0, const float* __restrict__ c0,
                 const float* __restrict__ Ww, const float* __restrict__ Wf,
                 const float* __restrict__ Wc, const float* __restrict__ Wo,
                 char* __restrict__ ws) {
  __hip_bfloat16* WA  = (__hip_bfloat16*)ws;
  __hip_bfloat16* WB  = (__hip_bfloat16*)(ws + OFF_WB);
  __hip_bfloat16* hbf = (__hip_bfloat16*)(ws + OFF_HBF);
  unsigned*       bar = (unsigned*)(ws + OFF_BAR);

  const long long total = Z0 + Z1 + Z2 + Z3;
  for (long long idx = (long long)blockIdx.x * 256 + threadIdx.x; idx < total;
       idx += (long long)gridDim.x * 256) {
    if (idx < Z0) {
      int l  = (int)(idx & 63);
      int s  = (int)((idx >> 6) % 320);
      int cg = (int)(idx / (320 * 64));
      int g, kc;
      if (s < 96)       { g = 0; kc = s; }
      else if (s < 192) { g = 1; kc = s - 96; }
      else if (s < 256) { g = 2; kc = s - 192; }
      else              { g = 3; kc = s - 256; }
      int j  = cg * 16 + (l & 15);
      int kb = kc * 32 + ((l >> 4) << 3);
      const float* W; int rl;
      if (g == 0)      { W = Ww; rl = 3072; }
      else if (g == 1) { W = Wf; rl = 3072; }
      else if (g == 2) { W = Wc; rl = 2048; }
      else             { W = Wo; rl = 3072; }
      const float* src = W + (size_t)j * rl + kb;
      __hip_bfloat16* dst = WA + ((((size_t)cg * 4 + g) * 96 + kc) * 64 + l) * 8;
#pragma unroll
      for (int e = 0; e < 8; ++e) dst[e] = __float2bfloat16(src[e]);
    } else if (idx < Z0 + Z1) {
      long long q = idx - Z0;
      int l  = (int)(q & 63);
      int kc = (int)((q >> 6) & 7);
      int v  = (int)((q >> 9) & 3);
      int cg = (int)(q >> 11);
      int j  = cg * 16 + (l & 15);
      int k  = 2048 + v * 256 + kc * 32 + ((l >> 4) << 3);
      const float* src = Wo + (size_t)j * 3072 + k;
      __hip_bfloat16* dst = WB + ((((size_t)cg * 4 + v) * 8 + kc) * 64 + l) * 8;
#pragma unroll
      for (int e = 0; e < 8; ++e) dst[e] = __float2bfloat16(src[e]);
    } else if (idx < Z0 + Z1 + Z2) {
      int i = (int)(idx - (Z0 + Z1));
      hbf[i] = __float2bfloat16(h0[i]);
    } else {
      int i = (int)(idx - (Z0 + Z1 + Z2));
      bar[i] = 0u;
    }
  }
}

// ---------------------------------------------------------------------------
// main persistent kernel
// ---------------------------------------------------------------------------
__global__ __launch_bounds__(256, 1)
void lstm_kernel(const float* __restrict__ x,  const float* __restrict__ c0,
                 const float* __restrict__ bw, const float* __restrict__ bfg,
                 const float* __restrict__ bc, const float* __restrict__ bo,
                 float* __restrict__ out, char* __restrict__ ws) {
  __hip_bfloat16* hbf = (__hip_bfloat16*)(ws + OFF_HBF);
  char*           cbf = ws + OFF_CBF;
  unsigned*       hctr  = (unsigned*)(ws + OFF_BAR);          // + grp*64
  unsigned*       cflag = (unsigned*)(ws + OFF_BAR) + 4096;   // + (grp*64+cg)*16

  const int tid  = threadIdx.x;
  const int l    = tid & 63;
  const int wv   = tid >> 6;                         // wave = gate (A) / K-split (B)
  const int b    = blockIdx.x;
  const int cg   = ((b & 7) << 3) | ((b >> 3) & 7);  // XCD-partitioned col-group
  const int grp  = b >> 6;                           // batch row-group (0..3)
  const int col  = l & 15;
  const int kg   = l >> 4;
  const int row16 = col;                             // A-frag row within tile
  const int srow  = row16 & 7;                       // LDS swizzle key
  const int j    = (cg << 4) + col;

  const float* bptr = (wv == 0) ? bw : (wv == 1) ? bfg : (wv == 2) ? bc : bo;
  const float bias = bptr[j];

  const short8* BW = (const short8*)ws + ((size_t)(cg * 4 + wv)) * 96 * 64 + l;
  const short8* BO = (const short8*)(ws + OFF_WB) + ((size_t)(cg * 4 + wv)) * 8 * 64 + l;

  __shared__ __align__(16) char sx[32768];   // x tile  [16][1024] bf16, swizzled
  __shared__ __align__(16) char sh[32768];   // h tile
  __shared__ __align__(16) char sc_[32768];  // c tile (carried across steps)
  __shared__ float lds[5][16][17];

  // combine mapping: tid<128 owns (crow, 2 cols)
  const int crow = tid >> 3;
  const int cpr  = tid & 7;
  const int coff = ((grp * 16 + crow) << 10) + (cg << 4) + 2 * cpr;
  float c_reg0 = 0.f, c_reg1 = 0.f;
  if (tid < 128) { c_reg0 = c0[coff]; c_reg1 = c0[coff + 1]; }
  // producer targets: h row-major (R14), c slice-grouped (512B tile)
  char* cDst = cbf + ((size_t)(grp * 64 + cg)) * 512 + crow * 32 + cpr * 4;
  unsigned* myflag = cflag + (grp * 64 + cg) * 16;

  // ---- startup: stage c0 tile fp32->bf16 -> swizzled sc_ (R13 math) ----
  {
    const float* cs = c0 + (size_t)grp * 16384;
#pragma unroll
    for (int i = 0; i < 8; ++i) {
      int q = i * 256 + tid;
      const float* s = cs + q * 8;
      float4 f0 = *(const float4*)s;
      float4 f1 = *(const float4*)(s + 4);
      short8 v;
      v[0] = bfc(f0.x); v[1] = bfc(f0.y); v[2] = bfc(f0.z); v[3] = bfc(f0.w);
      v[4] = bfc(f1.x); v[5] = bfc(f1.y); v[6] = bfc(f1.z); v[7] = bfc(f1.w);
      int rw = q >> 7, kb = (q & 127) ^ (rw & 7);
      *(short8*)(sc_ + rw * 2048 + (kb << 4)) = v;
    }
  }
  // ---- startup: stage x(0) tile (consumed by xA at t=0) ----
  {
    const float* xs = x + (size_t)grp * 16384;
#pragma unroll
    for (int i = 0; i < 8; ++i) {
      int q = i * 256 + tid;
      const float* s = xs + q * 8;
      float4 f0 = *(const float4*)s;
      float4 f1 = *(const float4*)(s + 4);
      short8 v;
      v[0] = bfc(f0.x); v[1] = bfc(f0.y); v[2] = bfc(f0.z); v[3] = bfc(f0.w);
      v[4] = bfc(f1.x); v[5] = bfc(f1.y); v[6] = bfc(f1.z); v[7] = bfc(f1.w);
      int rw = q >> 7, kb = (q & 127) ^ (rw & 7);
      *(short8*)(sx + rw * 2048 + (kb << 4)) = v;
    }
  }

  // ---- pin recurrent-path weight fragments in registers (loop-invariant) ----
  short8 WH[32];
#pragma unroll
  for (int f = 0; f < 32; ++f) WH[f] = BW[(size_t)(32 + f) * 64];
  short8 WBo[8];
#pragma unroll
  for (int k = 0; k < 8; ++k) WBo[k] = BO[(size_t)k * 64];

  __syncthreads();                     // startup sx/sc_ visible block-wide

  for (int t = 0; t < 512; ++t) {
    const int p = t & 1;
    const __hip_bfloat16* hb = hbf + (size_t)p * 65536;
    __hip_bfloat16* hbn = hbf + (size_t)(p ^ 1) * 65536;
    char* cslotW = cbf + (size_t)(p ^ 1) * 131072;   // c_new slot this step

    f32x4 acc[4];
#pragma unroll
    for (int u = 0; u < 4; ++u) acc[u] = (f32x4){0.f, 0.f, 0.f, 0.f};

    // ---- phase A, x part (sx staged in prev iter's c-gap / startup) ----
#pragma unroll
    for (int kc = 0; kc < 8; ++kc)
#pragma unroll
      for (int u = 0; u < 4; ++u) {
        int f = kc * 4 + u;
        short8 a = *(const short8*)(sx + row16 * 2048 + ((((f << 2) + kg) ^ srow) << 4));
        acc[u] = __builtin_amdgcn_mfma_f32_16x16x32_bf16(a, BW[(size_t)f * 64], acc[u], 0, 0, 0);
      }
    // ---- phase A, c part (write & forget gates) — pre-wait (R14) ----
    if (wv < 2) {
#pragma unroll
      for (int kc = 0; kc < 8; ++kc)
#pragma unroll
        for (int u = 0; u < 4; ++u) {
          int f = kc * 4 + u;
          short8 a = *(const short8*)(sc_ + row16 * 2048 + ((((f << 2) + kg) ^ srow) << 4));
          acc[u] = __builtin_amdgcn_mfma_f32_16x16x32_bf16(a, BW[(size_t)(64 + f) * 64], acc[u], 0, 0, 0);
        }
    }

    // ---- h wait: counter reaches 64*t (h(t-1) posted by all producers) ----
    if (tid == 0) {
      const unsigned tgt = (unsigned)t * 64u;
      unsigned spins = 0;
      for (;;) {
        unsigned v = poll_sc(hctr + grp * 64);
        if (v >= tgt) break;
        __builtin_amdgcn_s_sleep(1);
        if (++spins > (1u << 18)) break;             // failsafe: fail loud
      }
    }
    __syncthreads();
    __builtin_amdgcn_sched_barrier(0);

    // ---- stage h tile: sc0/sc1 loads -> swizzled LDS (R14) ----
    {
      const char* hsrc = (const char*)hb + (size_t)grp * 32768;
      uint4v th[8];
#pragma unroll
      for (int i = 0; i < 8; ++i)
        th[i] = ldg_sc(hsrc + (size_t)(i * 256 + tid) * 16);
      asm volatile("s_waitcnt vmcnt(0)" ::: "memory");
      __builtin_amdgcn_sched_barrier(0);
#pragma unroll
      for (int i = 0; i < 8; ++i) {
        int q = i * 256 + tid;
        int rw = q >> 7, kb = (q & 127) ^ (rw & 7);
        *(uint4v*)(sh + rw * 2048 + (kb << 4)) = th[i];
      }
    }
    __syncthreads();

    // ---- phase A, h part (all gates) — register-pinned fragments ----
#pragma unroll
    for (int kc = 0; kc < 8; ++kc)
#pragma unroll
      for (int u = 0; u < 4; ++u) {
        int f = kc * 4 + u;
        short8 a = *(const short8*)(sh + row16 * 2048 + ((((f << 2) + kg) ^ srow) << 4));
        acc[u] = __builtin_amdgcn_mfma_f32_16x16x32_bf16(a, WH[f], acc[u], 0, 0, 0);
      }
    {
      const int dbuf = (wv == 3) ? 4 : wv;
#pragma unroll
      for (int i = 0; i < 4; ++i)
        lds[dbuf][kg * 4 + i][col] = acc[0][i] + acc[1][i] + acc[2][i] + acc[3][i] + bias;
    }
    __syncthreads();

    // ---- c_new combine; slice-grouped store (512B contiguous/block) ----
    if (tid < 128) {
      float aw0 = lds[0][crow][2 * cpr], aw1 = lds[0][crow][2 * cpr + 1];
      float af0 = lds[1][crow][2 * cpr], af1 = lds[1][crow][2 * cpr + 1];
      float ag0 = lds[2][crow][2 * cpr], ag1 = lds[2][crow][2 * cpr + 1];
      float cn0 = sig_fast(af0) * c_reg0 + sig_fast(aw0) * tanh_fast(ag0);
      float cn1 = sig_fast(af1) * c_reg1 + sig_fast(aw1) * tanh_fast(ag1);
      c_reg0 = cn0; c_reg1 = cn1;
      stg_u32_sc((unsigned*)(cDst + (size_t)(p ^ 1) * 131072), pk2(cn0, cn1));
    }
    // arrive(c): drain + block-sync + per-producer flag (value t+1)
    asm volatile("s_waitcnt vmcnt(0)" ::: "memory");
    __syncthreads();
    if (tid == 0) stg_u32_sc(myflag, (unsigned)t + 1u);

    // ---- fill the c-exchange gap: stage x(t+1) (sx dead here) ----
    if (t < 511) {
      const float* xs = x + (((size_t)t + 1) << 16) + (size_t)grp * 16384;
#pragma unroll
      for (int i = 0; i < 8; ++i) {
        int q = i * 256 + tid;
        const float* s = xs + q * 8;
        float4 f0 = *(const float4*)s;
        float4 f1 = *(const float4*)(s + 4);
        short8 v;
        v[0] = bfc(f0.x); v[1] = bfc(f0.y); v[2] = bfc(f0.z); v[3] = bfc(f0.w);
        v[4] = bfc(f1.x); v[5] = bfc(f1.y); v[6] = bfc(f1.z); v[7] = bfc(f1.w);
        int rw = q >> 7, kb = (q & 127) ^ (rw & 7);
        *(short8*)(sx + rw * 2048 + (kb << 4)) = v;
      }
    }

    // ---- WAVE-LOCAL c wait: lanes 0-15 poll this wave's 16 producers ----
    if (l < 16) {
      const unsigned* pf = cflag + (grp * 64 + wv * 16 + l) * 16;
      const unsigned want = (unsigned)t + 1u;
      unsigned spins = 0;
      for (;;) {
        unsigned v = poll_sc(pf);
        if (__all((int)(v >= want))) break;
        __builtin_amdgcn_s_sleep(1);
        if (++spins > (1u << 18)) break;             // failsafe: fail loud
      }
    }
    __builtin_amdgcn_sched_barrier(0);

    // ---- phase B: slice-layout c pull (wave-local slices) -> MFMA; carry ----
    {
      const char* cslot = cslotW + (size_t)grp * 32768 + row16 * 32 + (kg & 1) * 16;
      uint4v ca[8];
#pragma unroll
      for (int kcc = 0; kcc < 8; ++kcc) {
        int s = wv * 16 + kcc * 2 + (kg >> 1);
        ca[kcc] = ldg_sc(cslot + (size_t)s * 512);
      }
      asm volatile("s_waitcnt vmcnt(0)" ::: "memory");
      __builtin_amdgcn_sched_barrier(0);
      f32x4 a0 = {0.f, 0.f, 0.f, 0.f}, a1 = {0.f, 0.f, 0.f, 0.f};
#pragma unroll
      for (int kcc = 0; kcc < 8; ++kcc) {
        short8 a = __builtin_bit_cast(short8, ca[kcc]);
        if (kcc & 1) a1 = __builtin_amdgcn_mfma_f32_16x16x32_bf16(a, WBo[kcc], a1, 0, 0, 0);
        else         a0 = __builtin_amdgcn_mfma_f32_16x16x32_bf16(a, WBo[kcc], a0, 0, 0, 0);
      }
      // carry write: unit = wv*32 + kcc*4 + kg (verified bijection over tid)
      const int ub = wv * 32 + kg;
#pragma unroll
      for (int kcc = 0; kcc < 8; ++kcc)
        *(uint4v*)(sc_ + row16 * 2048 + (((ub + kcc * 4) ^ srow) << 4)) = ca[kcc];
#pragma unroll
      for (int i = 0; i < 4; ++i)
        lds[wv][kg * 4 + i][col] = a0[i] + a1[i];
    }
    __syncthreads();

    // ---- o combine, h_new; h store (row-major); drain; bump h counter ----
    float h0v = 0.f, h1v = 0.f;
    if (tid < 128) {
      int c0i = 2 * cpr, c1i = 2 * cpr + 1;
      float s0 = lds[0][crow][c0i] + lds[1][crow][c0i] + lds[2][crow][c0i] +
                 lds[3][crow][c0i] + lds[4][crow][c0i];
      float s1 = lds[0][crow][c1i] + lds[1][crow][c1i] + lds[2][crow][c1i] +
                 lds[3][crow][c1i] + lds[4][crow][c1i];
      float o0 = sig_fast(s0), o1 = sig_fast(s1);
      h0v = o0 * tanh_fast(c_reg0);
      h1v = o1 * tanh_fast(c_reg1);
      stg_u32_sc((unsigned*)((char*)hbn + 2 * (size_t)coff), pk2(h0v, h1v));
    }
    asm volatile("s_waitcnt vmcnt(0)" ::: "memory");   // own h tile at L3
    __syncthreads();
    if (tid == 0)
      __hip_atomic_fetch_add(hctr + grp * 64, 1u,
                             __ATOMIC_RELAXED, __HIP_MEMORY_SCOPE_AGENT);

    if (tid < 128) {
      float2 hv; hv.x = h0v; hv.y = h1v;
      *(float2*)(out + ((size_t)t << 16) + coff) = hv;
      if (t == 511) {                    // finals: owner writes directly
        *(float2*)(out + ((size_t)512 << 16) + coff) = hv;
        float2 cv; cv.x = c_reg0; cv.y = c_reg1;
        *(float2*)(out + ((size_t)512 << 16) + 65536 + coff) = cv;
      }
    }
  }
}

extern "C" void kernel_launch(void* const* d_in, const int* in_sizes, int n_in,
                              void* d_out, int out_size, void* d_ws, size_t ws_size,
                              hipStream_t stream) {
  (void)in_sizes; (void)n_in; (void)out_size;
  const float* x  = (const float*)d_in[0];
  const float* h0 = (const float*)d_in[1];
  const float* c0 = (const float*)d_in[2];
  const float* Ww = (const float*)d_in[3];
  const float* bw = (const float*)d_in[4];
  const float* Wf = (const float*)d_in[5];
  const float* bfg= (const float*)d_in[6];
  const float* Wc = (const float*)d_in[7];
  const float* bc = (const float*)d_in[8];
  const float* Wo = (const float*)d_in[9];
  const float* bo = (const float*)d_in[10];

  if (ws_size < (size_t)WS_NEED) return;  // leaves poison -> loud failure

  prep_kernel<<<dim3(2048), dim3(256), 0, stream>>>(h0, c0, Ww, Wf, Wc, Wo,
                                                    (char*)d_ws);
  lstm_kernel<<<dim3(256), dim3(256), 0, stream>>>(x, c0, bw, bfg, bc, bo,
                                                   (float*)d_out, (char*)d_ws);
}